// Round 3
// baseline (71.666 us; speedup 1.0000x reference)
//
#include <hip/hip_runtime.h>

#define NN 4096
#define COL4 (NN / 4)      // 1024 float4 per row
#define BB 8
#define F_IN 40
#define HH 64
#define KW 5
#define LL (NN - KW + 1)   // 4092
#define RC 32              // row chunks for A passes (128 rows each)
#define CHUNK (NN / RC)    // 128
#define PC 16              // p-chunks for x contraction
#define PCH (NN / PC)      // 256
#define PCH4 (PCH / 4)     // 64

// workspace layout (in floats)
#define OFF_P1 0                           // [RC][NN]     partial colsums
#define OFF_PE (OFF_P1 + RC * NN)          // [RC][8][NN]  partial e_s vectors
#define OFF_PD (OFF_PE + RC * 8 * NN)      // [RC][NN]     partial d
#define OFF_M  (OFF_PD + RC * NN)          // [9][F_IN]    adjoint map
#define OFF_C0 (OFF_M + 9 * F_IN)          // [1]
#define OFF_SP (OFF_C0 + 1)                // [BB][PC]     per-chunk dot partials
// total = 1,311,209 floats = 5.24 MB

__device__ __forceinline__ int special_row(int s) { return s < 4 ? s : (NN - 8 + s); }
__device__ __forceinline__ void f4add(float4& a, const float4& b) {
    a.x += b.x; a.y += b.y; a.z += b.z; a.w += b.w;
}
__device__ __forceinline__ void f4fma(float4& a, float w, const float4& b) {
    a.x += w * b.x; a.y += w * b.y; a.z += w * b.z; a.w += w * b.w;
}

// Pass 1 over A: partial colsums + partial e_s (s=0..7). grid (16, RC), block (64,4)
__global__ __launch_bounds__(256) void kA(const float4* __restrict__ A4,
                                          const float* __restrict__ A,
                                          float4* __restrict__ part1,
                                          float4* __restrict__ partE) {
    __shared__ float w[8][CHUNK];          // special-row weights, 4 KB
    __shared__ float4 red[4][9][64];       // 36 KB
    int tx = threadIdx.x, ty = threadIdx.y;
    int tid = ty * 64 + tx;
    int m0 = blockIdx.y * CHUNK;
    for (int idx = tid; idx < 8 * CHUNK; idx += 256) {
        int s = idx >> 7, j = idx & 127;
        w[s][j] = A[(size_t)special_row(s) * NN + m0 + j];
    }
    __syncthreads();
    int c4 = blockIdx.x * 64 + tx;
    const float4* Ap = A4 + (size_t)(m0 + ty * 32) * COL4 + c4;
    float4 acc[9];
    #pragma unroll
    for (int v = 0; v < 9; ++v) acc[v] = make_float4(0.f, 0.f, 0.f, 0.f);
    #pragma unroll 4
    for (int j = 0; j < 32; ++j) {
        float4 a = Ap[(size_t)j * COL4];
        int jj = ty * 32 + j;
        f4add(acc[0], a);
        #pragma unroll
        for (int s = 0; s < 8; ++s) f4fma(acc[1 + s], w[s][jj], a);
    }
    #pragma unroll
    for (int v = 0; v < 9; ++v) red[ty][v][tx] = acc[v];
    __syncthreads();
    if (ty == 0) {
        #pragma unroll
        for (int v = 0; v < 9; ++v) {
            float4 t = red[0][v][tx];
            f4add(t, red[1][v][tx]);
            f4add(t, red[2][v][tx]);
            f4add(t, red[3][v][tx]);
            if (v == 0) part1[(size_t)blockIdx.y * COL4 + c4] = t;
            else        partE[((size_t)blockIdx.y * 8 + (v - 1)) * COL4 + c4] = t;
        }
    }
}

// Pass 2 over A: partial d (weights = on-the-fly-reduced c) ; block 512 = adjoint.
// grid 513, block 256
__global__ __launch_bounds__(256) void kC(const float4* __restrict__ A4,
                                          const float* __restrict__ part1f,
                                          float4* __restrict__ partD,
                                          const float* __restrict__ W1, const float* __restrict__ b1,
                                          const float* __restrict__ W2, const float* __restrict__ b2,
                                          const float* __restrict__ cw, const float* __restrict__ cb,
                                          const float* __restrict__ fw, const float* __restrict__ fb,
                                          float* __restrict__ Mout, float* __restrict__ c0out) {
    int tid = threadIdx.x;
    if (blockIdx.x < 512) {
        int bx = blockIdx.x & 15, by = blockIdx.x >> 4;
        int tx = tid & 63, ty = tid >> 6;
        __shared__ float cs[CHUNK];
        __shared__ float4 redd[4][64];
        int m0 = by * CHUNK;
        if (tid < CHUNK) {
            float s = 0.f;
            #pragma unroll 8
            for (int y = 0; y < RC; ++y) s += part1f[(size_t)y * NN + m0 + tid];
            cs[tid] = s;
        }
        __syncthreads();
        int c4 = bx * 64 + tx;
        const float4* Ap = A4 + (size_t)(m0 + ty * 32) * COL4 + c4;
        float4 acc = {0.f, 0.f, 0.f, 0.f};
        #pragma unroll 8
        for (int j = 0; j < 32; ++j) f4fma(acc, cs[ty * 32 + j], Ap[(size_t)j * COL4]);
        redd[ty][tx] = acc;
        __syncthreads();
        if (ty == 0) {
            float4 t = redd[0][tx];
            f4add(t, redd[1][tx]);
            f4add(t, redd[2][tx]);
            f4add(t, redd[3][tx]);
            partD[(size_t)by * COL4 + c4] = t;
        }
        return;
    }
    // ---- adjoint block ----
    int wv = tid >> 6, lane = tid & 63;
    __shared__ float r[8];
    __shared__ float sC_s;
    __shared__ float red[256];
    __shared__ float Xp[4][9][64];
    __shared__ float X[9][64];
    __shared__ float P[9][64];
    __shared__ float bw2[64];

    // r[8]: rowsums of the special rows
    for (int pass = 0; pass < 2; ++pass) {
        int s = wv + pass * 4;
        const float4* Ar = A4 + (size_t)special_row(s) * COL4;
        float acc = 0.f;
        #pragma unroll 4
        for (int j = lane; j < COL4; j += 64) {
            float4 a = Ar[j];
            acc += a.x + a.y + a.z + a.w;
        }
        for (int off = 32; off > 0; off >>= 1) acc += __shfl_down(acc, off);
        if (lane == 0) r[s] = acc;
    }
    // sC = total sum of part1 (= sum of all of A)
    {
        const float4* p14 = (const float4*)part1f;
        float s = 0.f;
        #pragma unroll 4
        for (int j = tid; j < RC * COL4; j += 256) {
            float4 a = p14[j];
            s += a.x + a.y + a.z + a.w;
        }
        red[tid] = s;
        __syncthreads();
        for (int off = 128; off > 0; off >>= 1) {
            if (tid < off) red[tid] += red[tid + off];
            __syncthreads();
        }
        if (tid == 0) sC_s = red[0];
    }
    // X[0][i]=G[i], X[1+s][i]=H_s[i]: conv-window adjoint coefficients
    {
        int og = tid >> 6, i = tid & 63;
        float accG = 0.f, accH[8] = {0.f,0.f,0.f,0.f,0.f,0.f,0.f,0.f};
        for (int oo = 0; oo < 16; ++oo) {
            int o = og * 16 + oo;
            float f = fw[o];
            const float* cwp = cw + ((size_t)o * HH + i) * KW;
            float w0 = cwp[0], w1 = cwp[1], w2 = cwp[2], w3 = cwp[3], w4 = cwp[4];
            accG += f * (w0 + w1 + w2 + w3 + w4);
            accH[0] += f * (w1 + w2 + w3 + w4);
            accH[1] += f * (w2 + w3 + w4);
            accH[2] += f * (w3 + w4);
            accH[3] += f * w4;
            accH[4] += f * w0;
            accH[5] += f * (w0 + w1);
            accH[6] += f * (w0 + w1 + w2);
            accH[7] += f * (w0 + w1 + w2 + w3);
        }
        Xp[og][0][i] = accG;
        #pragma unroll
        for (int s = 0; s < 8; ++s) Xp[og][1 + s][i] = accH[s];
    }
    __syncthreads();
    for (int t = tid; t < 9 * 64; t += 256) {
        int v = t >> 6, i = t & 63;
        float s = Xp[0][v][i] + Xp[1][v][i] + Xp[2][v][i] + Xp[3][v][i];
        X[v][i] = (v == 0 ? 1.f : -1.f) * s / (float)LL;
    }
    __syncthreads();
    // P[v][h] = sum_i X[v][i] * W2[h,i]
    for (int t = tid; t < 9 * 64; t += 256) {
        int v = t >> 6, h = t & 63;
        const float4* W2r = (const float4*)(W2 + (size_t)h * HH);
        float s = 0.f;
        #pragma unroll 4
        for (int ii = 0; ii < 16; ++ii) {
            float4 a = W2r[ii];
            s += a.x * X[v][ii * 4] + a.y * X[v][ii * 4 + 1]
               + a.z * X[v][ii * 4 + 2] + a.w * X[v][ii * 4 + 3];
        }
        P[v][h] = s;
    }
    // bw2[i] = sum_h b1[h] * W2[h,i]
    if (tid < 64) {
        float s = 0.f;
        for (int h = 0; h < HH; ++h) s += b1[h] * W2[(size_t)h * HH + tid];
        bw2[tid] = s;
    }
    __syncthreads();
    // M[v][f] = sum_h P[v][h] * W1[f,h]
    for (int t = tid; t < 9 * F_IN; t += 256) {
        int v = t / F_IN, f = t % F_IN;
        const float4* W1r = (const float4*)(W1 + (size_t)f * HH);
        float s = 0.f;
        #pragma unroll 4
        for (int hh = 0; hh < 16; ++hh) {
            float4 a = W1r[hh];
            s += a.x * P[v][hh * 4] + a.y * P[v][hh * 4 + 1]
               + a.z * P[v][hh * 4 + 2] + a.w * P[v][hh * 4 + 3];
        }
        Mout[t] = s;
    }
    // c0
    {
        float sC = sC_s;
        float part = 0.f;
        for (int t = tid; t < 9 * 64; t += 256) {
            int v = t >> 6, i = t & 63;
            float base = (v == 0) ? (sC * bw2[i] + (float)NN * b2[i])
                                  : (r[v - 1] * bw2[i] + b2[i]);
            part += X[v][i] * base;
        }
        if (tid < 64) part += fw[tid] * cb[tid];
        red[tid] = part;
        __syncthreads();
        for (int off = 128; off > 0; off >>= 1) {
            if (tid < off) red[tid] += red[tid + off];
            __syncthreads();
        }
        if (tid == 0) c0out[0] = red[0] + fb[0];
    }
}

// x-contraction with on-the-fly partial reduction + dot with M.
// grid (BB, PC), block 256
__global__ __launch_bounds__(256) void kE(const float* __restrict__ x,
                                          const float* __restrict__ partDf,
                                          const float* __restrict__ partEf,
                                          const float* __restrict__ M,
                                          float* __restrict__ spart) {
    __shared__ float xs[PCH * F_IN];   // 40 KB
    __shared__ float wls[9][PCH];      // 9 KB
    __shared__ float Ms[9 * F_IN];
    __shared__ float red[256];
    int b = blockIdx.x, pc = blockIdx.y;
    int tid = threadIdx.x;
    int p0 = pc * PCH;
    const float4* xsrc4 = (const float4*)(x + ((size_t)b * NN + p0) * F_IN);
    float4* xs4 = (float4*)xs;
    #pragma unroll 4
    for (int idx = tid; idx < PCH * F_IN / 4; idx += 256) xs4[idx] = xsrc4[idx];
    // reduce weights: v=0 from partD, v=1+s from partE
    for (int idx = tid; idx < 9 * PCH4; idx += 256) {
        int v = idx / PCH4, j4 = idx % PCH4;
        const float4* src = (v == 0)
            ? (const float4*)partDf + (size_t)0 * COL4 + pc * PCH4 + j4
            : (const float4*)partEf + (size_t)(v - 1) * COL4 + pc * PCH4 + j4;
        float4 s = {0.f, 0.f, 0.f, 0.f};
        if (v == 0) {
            #pragma unroll 8
            for (int y = 0; y < RC; ++y)
                f4add(s, ((const float4*)partDf)[(size_t)y * COL4 + pc * PCH4 + j4]);
        } else {
            #pragma unroll 8
            for (int y = 0; y < RC; ++y)
                f4add(s, ((const float4*)partEf)[((size_t)y * 8 + (v - 1)) * COL4 + pc * PCH4 + j4]);
        }
        (void)src;
        ((float4*)&wls[v][0])[j4] = s;
    }
    for (int idx = tid; idx < 9 * F_IN; idx += 256) Ms[idx] = M[idx];
    __syncthreads();
    float part = 0.f;
    for (int o = tid; o < 9 * F_IN; o += 256) {
        int v = o / F_IN, f = o % F_IN;
        float s = 0.f;
        for (int j = 0; j < PCH; ++j) s += wls[v][j] * xs[j * F_IN + f];
        part += Ms[o] * s;
    }
    red[tid] = part;
    __syncthreads();
    for (int off = 128; off > 0; off >>= 1) {
        if (tid < off) red[tid] += red[tid + off];
        __syncthreads();
    }
    if (tid == 0) spart[(size_t)b * PC + pc] = red[0];
}

// Final: out[b] = c0 + sum_pc spart[b][pc]. grid 1, block 128
__global__ void kF(const float* __restrict__ spart, const float* __restrict__ c0p,
                   float* __restrict__ out) {
    int tid = threadIdx.x;
    int b = tid >> 4, i = tid & 15;
    float s = spart[b * PC + i];
    for (int off = 8; off > 0; off >>= 1) s += __shfl_down(s, off, 16);
    if (i == 0) out[b] = c0p[0] + s;
}

extern "C" void kernel_launch(void* const* d_in, const int* in_sizes, int n_in,
                              void* d_out, int out_size, void* d_ws, size_t ws_size,
                              hipStream_t stream) {
    const float* x  = (const float*)d_in[0];
    const float* A  = (const float*)d_in[1];
    const float* W1 = (const float*)d_in[2];
    const float* b1 = (const float*)d_in[3];
    const float* W2 = (const float*)d_in[4];
    const float* b2 = (const float*)d_in[5];
    const float* cw = (const float*)d_in[6];
    const float* cb = (const float*)d_in[7];
    const float* fw = (const float*)d_in[8];
    const float* fb = (const float*)d_in[9];
    float* out = (float*)d_out;
    float* ws = (float*)d_ws;

    float* part1 = ws + OFF_P1;
    float* partE = ws + OFF_PE;
    float* partD = ws + OFF_PD;
    float* Mmat  = ws + OFF_M;
    float* c0p   = ws + OFF_C0;
    float* spart = ws + OFF_SP;

    const float4* A4 = (const float4*)A;

    kA<<<dim3(16, RC), dim3(64, 4), 0, stream>>>(A4, A, (float4*)part1, (float4*)partE);
    kC<<<dim3(513), 256, 0, stream>>>(A4, part1, (float4*)partD,
                                      W1, b1, W2, b2, cw, cb, fw, fb, Mmat, c0p);
    kE<<<dim3(BB, PC), 256, 0, stream>>>(x, partD, partE, Mmat, spart);
    kF<<<dim3(1), 128, 0, stream>>>(spart, c0p, out);
}

// Round 4
// 61.105 us; speedup vs baseline: 1.1728x; 1.1728x over previous
//
#include <hip/hip_runtime.h>

#define NN 4096
#define COL4 (NN / 4)      // 1024 float4 per row
#define BB 8
#define F_IN 40
#define HH 64
#define KW 5
#define LL (NN - KW + 1)   // 4092
#define RC 32              // row chunks for A passes (128 rows each)
#define CHUNK (NN / RC)    // 128
#define PC 16              // p-chunks for x contraction
#define PCH (NN / PC)      // 256
#define PCH4 (PCH / 4)     // 64

// workspace layout (in floats)
#define OFF_P1 0                           // [RC][NN]     partial colsums
#define OFF_PE (OFF_P1 + RC * NN)          // [RC][8][NN]  partial e_s vectors
#define OFF_PD (OFF_PE + RC * 8 * NN)      // [RC][NN]     partial d
#define OFF_M  (OFF_PD + RC * NN)          // [9][F_IN]    adjoint map M
#define OFF_AB (OFF_M + 9 * F_IN)          // [10]         alpha, beta[8], gamma
#define OFF_RP (OFF_AB + 10)               // [8][16]      rpart (special-row col-group sums)
#define OFF_SC (OFF_RP + 8 * 16)           // [32]         per-row-chunk sums of c
#define OFF_SP (OFF_SC + 32)               // [BB][PC]     per-chunk dot partials

__device__ __forceinline__ int special_row(int s) { return s < 4 ? s : (NN - 8 + s); }
__device__ __forceinline__ void f4add(float4& a, const float4& b) {
    a.x += b.x; a.y += b.y; a.z += b.z; a.w += b.w;
}
__device__ __forceinline__ void f4fma(float4& a, float w, const float4& b) {
    a.x += w * b.x; a.y += w * b.y; a.z += w * b.z; a.w += w * b.w;
}

// Pass 1 over A: blocks 0..511: partial colsums + partial e_s + rpart.
// Block 512: weights-only adjoint (M, alpha/beta/gamma) — no A access, hides
// under the streaming blocks. grid 513, block (64,4).
__global__ __launch_bounds__(256) void kA(const float4* __restrict__ A4,
                                          const float* __restrict__ A,
                                          float4* __restrict__ part1,
                                          float4* __restrict__ partE,
                                          float* __restrict__ rpart,
                                          const float* __restrict__ W1, const float* __restrict__ b1,
                                          const float* __restrict__ W2, const float* __restrict__ b2,
                                          const float* __restrict__ cw, const float* __restrict__ cb,
                                          const float* __restrict__ fw, const float* __restrict__ fb,
                                          float* __restrict__ Mout, float* __restrict__ abg) {
    int tx = threadIdx.x, ty = threadIdx.y;
    int tid = ty * 64 + tx;
    if (blockIdx.x < 512) {
        __shared__ float w[8][CHUNK];          // special-row weights, 4 KB
        __shared__ float4 red[4][9][64];       // 36 KB
        int bx = blockIdx.x & 15, by = blockIdx.x >> 4;
        int m0 = by * CHUNK;
        for (int idx = tid; idx < 8 * CHUNK; idx += 256) {
            int s = idx >> 7, j = idx & 127;
            w[s][j] = A[(size_t)special_row(s) * NN + m0 + j];
        }
        __syncthreads();
        int c4 = bx * 64 + tx;
        const float4* Ap = A4 + (size_t)(m0 + ty * 32) * COL4 + c4;
        float4 acc[9];
        #pragma unroll
        for (int v = 0; v < 9; ++v) acc[v] = make_float4(0.f, 0.f, 0.f, 0.f);
        #pragma unroll 4
        for (int j = 0; j < 32; ++j) {
            float4 a = Ap[(size_t)j * COL4];
            int jj = ty * 32 + j;
            f4add(acc[0], a);
            #pragma unroll
            for (int s = 0; s < 8; ++s) f4fma(acc[1 + s], w[s][jj], a);
        }
        #pragma unroll
        for (int v = 0; v < 9; ++v) red[ty][v][tx] = acc[v];
        __syncthreads();
        if (ty == 0) {
            #pragma unroll
            for (int v = 0; v < 9; ++v) {
                float4 t = red[0][v][tx];
                f4add(t, red[1][v][tx]);
                f4add(t, red[2][v][tx]);
                f4add(t, red[3][v][tx]);
                if (v == 0) part1[(size_t)by * COL4 + c4] = t;
                else        partE[((size_t)by * 8 + (v - 1)) * COL4 + c4] = t;
            }
            // special-row column-group partial rowsums (L1/L2-hot re-reads)
            if (by == 0 || by == 31) {
                int sbase = (by == 0) ? 0 : 4;
                #pragma unroll
                for (int k = 0; k < 4; ++k) {
                    float4 a = A4[(size_t)special_row(sbase + k) * COL4 + c4];
                    float v = a.x + a.y + a.z + a.w;
                    for (int off = 32; off > 0; off >>= 1) v += __shfl_down(v, off);
                    if (tx == 0) rpart[(sbase + k) * 16 + bx] = v;
                }
            }
        }
        return;
    }
    // ---- weights-only adjoint block ----
    __shared__ float Xp[4][9][64];
    __shared__ float X[9][64];
    __shared__ float P[9][64];
    __shared__ float bw2[64];
    {
        int og = tid >> 6, i = tid & 63;
        float accG = 0.f, accH[8] = {0.f,0.f,0.f,0.f,0.f,0.f,0.f,0.f};
        for (int oo = 0; oo < 16; ++oo) {
            int o = og * 16 + oo;
            float f = fw[o];
            const float* cwp = cw + ((size_t)o * HH + i) * KW;
            float w0 = cwp[0], w1 = cwp[1], w2 = cwp[2], w3 = cwp[3], w4 = cwp[4];
            accG += f * (w0 + w1 + w2 + w3 + w4);
            accH[0] += f * (w1 + w2 + w3 + w4);
            accH[1] += f * (w2 + w3 + w4);
            accH[2] += f * (w3 + w4);
            accH[3] += f * w4;
            accH[4] += f * w0;
            accH[5] += f * (w0 + w1);
            accH[6] += f * (w0 + w1 + w2);
            accH[7] += f * (w0 + w1 + w2 + w3);
        }
        Xp[og][0][i] = accG;
        #pragma unroll
        for (int s = 0; s < 8; ++s) Xp[og][1 + s][i] = accH[s];
    }
    __syncthreads();
    for (int t = tid; t < 9 * 64; t += 256) {
        int v = t >> 6, i = t & 63;
        float s = Xp[0][v][i] + Xp[1][v][i] + Xp[2][v][i] + Xp[3][v][i];
        X[v][i] = (v == 0 ? 1.f : -1.f) * s / (float)LL;
    }
    __syncthreads();
    // P[v][h] = sum_i X[v][i] * W2[h,i]
    for (int t = tid; t < 9 * 64; t += 256) {
        int v = t >> 6, h = t & 63;
        const float4* W2r = (const float4*)(W2 + (size_t)h * HH);
        float s = 0.f;
        #pragma unroll 4
        for (int ii = 0; ii < 16; ++ii) {
            float4 a = W2r[ii];
            s += a.x * X[v][ii * 4] + a.y * X[v][ii * 4 + 1]
               + a.z * X[v][ii * 4 + 2] + a.w * X[v][ii * 4 + 3];
        }
        P[v][h] = s;
    }
    // bw2[i] = sum_h b1[h] * W2[h,i]
    if (tid < 64) {
        float s = 0.f;
        for (int h = 0; h < HH; ++h) s += b1[h] * W2[(size_t)h * HH + tid];
        bw2[tid] = s;
    }
    __syncthreads();
    // M[v][f] = sum_h P[v][h] * W1[f,h]
    for (int t = tid; t < 9 * F_IN; t += 256) {
        int v = t / F_IN, f = t % F_IN;
        const float4* W1r = (const float4*)(W1 + (size_t)f * HH);
        float s = 0.f;
        #pragma unroll 4
        for (int hh = 0; hh < 16; ++hh) {
            float4 a = W1r[hh];
            s += a.x * P[v][hh * 4] + a.y * P[v][hh * 4 + 1]
               + a.z * P[v][hh * 4 + 2] + a.w * P[v][hh * 4 + 3];
        }
        Mout[t] = s;
    }
    // alpha = X0·bw2 ; beta_s = X_{1+s}·bw2  (wave 0, one v at a time)
    if (tid < 64) {
        #pragma unroll
        for (int v = 0; v < 9; ++v) {
            float val = X[v][tid] * bw2[tid];
            for (int off = 32; off > 0; off >>= 1) val += __shfl_down(val, off);
            if (tid == 0) abg[v] = val;   // abg[0]=alpha, abg[1+s]=beta_s
        }
        // gamma
        float g = X[0][tid] * (float)NN * b2[tid] + fw[tid] * cb[tid];
        #pragma unroll
        for (int s = 0; s < 8; ++s) g += X[1 + s][tid] * b2[tid];
        for (int off = 32; off > 0; off >>= 1) g += __shfl_down(g, off);
        if (tid == 0) abg[9] = g + fb[0];
    }
}

// Pass 2 over A: partial d (weights = on-the-fly-reduced c) + per-chunk c sums.
// grid 512, block 256
__global__ __launch_bounds__(256) void kC(const float4* __restrict__ A4,
                                          const float* __restrict__ part1f,
                                          float4* __restrict__ partD,
                                          float* __restrict__ sCpart) {
    int tid = threadIdx.x;
    int bx = blockIdx.x & 15, by = blockIdx.x >> 4;
    int tx = tid & 63, ty = tid >> 6;
    __shared__ float cs[CHUNK];
    __shared__ float4 redd[4][64];
    int m0 = by * CHUNK;
    if (tid < CHUNK) {
        float s = 0.f;
        #pragma unroll 8
        for (int y = 0; y < RC; ++y) s += part1f[(size_t)y * NN + m0 + tid];
        cs[tid] = s;
    }
    __syncthreads();
    if (bx == 0 && tid < 64) {
        float t = cs[tid] + cs[tid + 64];
        for (int off = 32; off > 0; off >>= 1) t += __shfl_down(t, off);
        if (tid == 0) sCpart[by] = t;
    }
    int c4 = bx * 64 + tx;
    const float4* Ap = A4 + (size_t)(m0 + ty * 32) * COL4 + c4;
    float4 acc = {0.f, 0.f, 0.f, 0.f};
    #pragma unroll 8
    for (int j = 0; j < 32; ++j) f4fma(acc, cs[ty * 32 + j], Ap[(size_t)j * COL4]);
    redd[ty][tx] = acc;
    __syncthreads();
    if (ty == 0) {
        float4 t = redd[0][tx];
        f4add(t, redd[1][tx]);
        f4add(t, redd[2][tx]);
        f4add(t, redd[3][tx]);
        partD[(size_t)by * COL4 + c4] = t;
    }
}

// x-contraction with on-the-fly partial reduction + dot with M.
// grid (BB, PC), block 256
__global__ __launch_bounds__(256) void kE(const float* __restrict__ x,
                                          const float* __restrict__ partDf,
                                          const float* __restrict__ partEf,
                                          const float* __restrict__ M,
                                          float* __restrict__ spart) {
    __shared__ float xs[PCH * F_IN];   // 40 KB
    __shared__ float wls[9][PCH];      // 9 KB
    __shared__ float Ms[9 * F_IN];
    __shared__ float red[256];
    int b = blockIdx.x, pc = blockIdx.y;
    int tid = threadIdx.x;
    int p0 = pc * PCH;
    const float4* xsrc4 = (const float4*)(x + ((size_t)b * NN + p0) * F_IN);
    float4* xs4 = (float4*)xs;
    #pragma unroll 4
    for (int idx = tid; idx < PCH * F_IN / 4; idx += 256) xs4[idx] = xsrc4[idx];
    for (int idx = tid; idx < 9 * PCH4; idx += 256) {
        int v = idx / PCH4, j4 = idx % PCH4;
        float4 s = {0.f, 0.f, 0.f, 0.f};
        if (v == 0) {
            #pragma unroll 8
            for (int y = 0; y < RC; ++y)
                f4add(s, ((const float4*)partDf)[(size_t)y * COL4 + pc * PCH4 + j4]);
        } else {
            #pragma unroll 8
            for (int y = 0; y < RC; ++y)
                f4add(s, ((const float4*)partEf)[((size_t)y * 8 + (v - 1)) * COL4 + pc * PCH4 + j4]);
        }
        ((float4*)&wls[v][0])[j4] = s;
    }
    for (int idx = tid; idx < 9 * F_IN; idx += 256) Ms[idx] = M[idx];
    __syncthreads();
    float part = 0.f;
    for (int o = tid; o < 9 * F_IN; o += 256) {
        int v = o / F_IN, f = o % F_IN;
        float s = 0.f;
        for (int j = 0; j < PCH; ++j) s += wls[v][j] * xs[j * F_IN + f];
        part += Ms[o] * s;
    }
    red[tid] = part;
    __syncthreads();
    for (int off = 128; off > 0; off >>= 1) {
        if (tid < off) red[tid] += red[tid + off];
        __syncthreads();
    }
    if (tid == 0) spart[(size_t)b * PC + pc] = red[0];
}

// Final: c0 = gamma + alpha*sC + sum_s beta_s*r_s ; out[b] = c0 + sum_pc spart.
// grid 1, block 128
__global__ void kF(const float* __restrict__ spart, const float* __restrict__ rpart,
                   const float* __restrict__ sCpart, const float* __restrict__ abg,
                   float* __restrict__ out) {
    int tid = threadIdx.x;
    __shared__ float red[128];
    __shared__ float c0s;
    float val = abg[1 + (tid >> 4)] * rpart[tid];   // beta_s * rpart[s][g]
    if (tid < 32) val += abg[0] * sCpart[tid];      // alpha * sC partials
    red[tid] = val;
    __syncthreads();
    for (int off = 64; off > 0; off >>= 1) {
        if (tid < off) red[tid] += red[tid + off];
        __syncthreads();
    }
    if (tid == 0) c0s = red[0] + abg[9];
    __syncthreads();
    float s = spart[tid];                            // b=tid>>4, i=tid&15
    for (int off = 8; off > 0; off >>= 1) s += __shfl_down(s, off, 16);
    if ((tid & 15) == 0) out[tid >> 4] = c0s + s;
}

extern "C" void kernel_launch(void* const* d_in, const int* in_sizes, int n_in,
                              void* d_out, int out_size, void* d_ws, size_t ws_size,
                              hipStream_t stream) {
    const float* x  = (const float*)d_in[0];
    const float* A  = (const float*)d_in[1];
    const float* W1 = (const float*)d_in[2];
    const float* b1 = (const float*)d_in[3];
    const float* W2 = (const float*)d_in[4];
    const float* b2 = (const float*)d_in[5];
    const float* cw = (const float*)d_in[6];
    const float* cb = (const float*)d_in[7];
    const float* fw = (const float*)d_in[8];
    const float* fb = (const float*)d_in[9];
    float* out = (float*)d_out;
    float* ws = (float*)d_ws;

    float* part1 = ws + OFF_P1;
    float* partE = ws + OFF_PE;
    float* partD = ws + OFF_PD;
    float* Mmat  = ws + OFF_M;
    float* abg   = ws + OFF_AB;
    float* rpart = ws + OFF_RP;
    float* sCpart= ws + OFF_SC;
    float* spart = ws + OFF_SP;

    const float4* A4 = (const float4*)A;

    kA<<<dim3(513), dim3(64, 4), 0, stream>>>(A4, A, (float4*)part1, (float4*)partE, rpart,
                                              W1, b1, W2, b2, cw, cb, fw, fb, Mmat, abg);
    kC<<<dim3(512), 256, 0, stream>>>(A4, part1, (float4*)partD, sCpart);
    kE<<<dim3(BB, PC), 256, 0, stream>>>(x, partD, partE, Mmat, spart);
    kF<<<dim3(1), 128, 0, stream>>>(spart, rpart, sCpart, abg, out);
}

// Round 5
// 54.623 us; speedup vs baseline: 1.3120x; 1.1187x over previous
//
#include <hip/hip_runtime.h>

#define NN 4096
#define COL4 (NN / 4)      // 1024 float4 per row
#define BB 8
#define F_IN 40
#define HH 64
#define KW 5
#define LL (NN - KW + 1)   // 4092
#define RC 32              // row chunks for A passes (128 rows each)
#define CHUNK (NN / RC)    // 128
#define PC 16              // p-chunks for x contraction
#define PCH (NN / PC)      // 256
#define PCH4 (PCH / 4)     // 64

// workspace layout (in floats)
#define OFF_P1 0                           // [RC][NN]     partial colsums
#define OFF_PE (OFF_P1 + RC * NN)          // [RC][8][NN]  partial e_s vectors
#define OFF_PD (OFF_PE + RC * 8 * NN)      // [RC][NN]     partial d
#define OFF_XP (OFF_PD + RC * NN)          // [64][9][64]  X partials (per out-channel o)
#define OFF_BW (OFF_XP + 64 * 9 * 64)      // [64]         bw2
#define OFF_M  (OFF_BW + 64)               // [9][F_IN]    adjoint map M
#define OFF_AB (OFF_M + 9 * F_IN)          // [9]          alpha, beta[8]
#define OFF_G9 (OFF_AB + 9)                // [9]          gamma pieces
#define OFF_RP (OFF_G9 + 9)                // [8][16]      rpart
#define OFF_SC (OFF_RP + 8 * 16)           // [32]         per-row-chunk sums of c
#define OFF_SP (OFF_SC + 32)               // [BB][PC]     per-chunk dot partials

__device__ __forceinline__ int special_row(int s) { return s < 4 ? s : (NN - 8 + s); }
__device__ __forceinline__ void f4add(float4& a, const float4& b) {
    a.x += b.x; a.y += b.y; a.z += b.z; a.w += b.w;
}
__device__ __forceinline__ void f4fma(float4& a, float w, const float4& b) {
    a.x += w * b.x; a.y += w * b.y; a.z += w * b.z; a.w += w * b.w;
}

// kA: blocks 0..511 stream A (colsum + e_s partials + rpart);
//     blocks 512..575: X-partials (one per conv out-channel o);
//     block 576: bw2. grid 577, block (64,4).
__global__ __launch_bounds__(256) void kA(const float4* __restrict__ A4,
                                          const float* __restrict__ A,
                                          float4* __restrict__ part1,
                                          float4* __restrict__ partE,
                                          float* __restrict__ rpart,
                                          const float* __restrict__ b1,
                                          const float* __restrict__ W2,
                                          const float* __restrict__ cw,
                                          const float* __restrict__ fw,
                                          float* __restrict__ Xpart,
                                          float* __restrict__ bw2) {
    int tx = threadIdx.x, ty = threadIdx.y;
    int tid = ty * 64 + tx;
    if (blockIdx.x < 512) {
        __shared__ float w[8][CHUNK];          // 4 KB
        __shared__ float4 red3[4][3][64];      // 12 KB (3-group staged reduction)
        int bx = blockIdx.x & 15, by = blockIdx.x >> 4;
        int m0 = by * CHUNK;
        for (int idx = tid; idx < 8 * CHUNK; idx += 256) {
            int s = idx >> 7, j = idx & 127;
            w[s][j] = A[(size_t)special_row(s) * NN + m0 + j];
        }
        __syncthreads();
        int c4 = bx * 64 + tx;
        const float4* Ap = A4 + (size_t)(m0 + ty * 32) * COL4 + c4;
        float4 acc[9];
        #pragma unroll
        for (int v = 0; v < 9; ++v) acc[v] = make_float4(0.f, 0.f, 0.f, 0.f);
        #pragma unroll 4
        for (int j = 0; j < 32; ++j) {
            float4 a = Ap[(size_t)j * COL4];
            int jj = ty * 32 + j;
            f4add(acc[0], a);
            #pragma unroll
            for (int s = 0; s < 8; ++s) f4fma(acc[1 + s], w[s][jj], a);
        }
        #pragma unroll
        for (int g = 0; g < 3; ++g) {
            #pragma unroll
            for (int vv = 0; vv < 3; ++vv) red3[ty][vv][tx] = acc[g * 3 + vv];
            __syncthreads();
            if (ty == 0) {
                #pragma unroll
                for (int vv = 0; vv < 3; ++vv) {
                    int v = g * 3 + vv;
                    float4 t = red3[0][vv][tx];
                    f4add(t, red3[1][vv][tx]);
                    f4add(t, red3[2][vv][tx]);
                    f4add(t, red3[3][vv][tx]);
                    if (v == 0) part1[(size_t)by * COL4 + c4] = t;
                    else        partE[((size_t)by * 8 + (v - 1)) * COL4 + c4] = t;
                }
            }
            __syncthreads();
        }
        // special-row column-group partial rowsums (L1/L2-hot re-reads)
        if ((by == 0 || by == 31) && ty == 0) {
            int sbase = (by == 0) ? 0 : 4;
            #pragma unroll
            for (int k = 0; k < 4; ++k) {
                float4 a = A4[(size_t)special_row(sbase + k) * COL4 + c4];
                float v = a.x + a.y + a.z + a.w;
                for (int off = 32; off > 0; off >>= 1) v += __shfl_down(v, off);
                if (tx == 0) rpart[(sbase + k) * 16 + bx] = v;
            }
        }
        return;
    }
    if (blockIdx.x < 576) {
        // X-partials for out-channel o: 9 window-adjoint coefficients per i
        int o = blockIdx.x - 512;
        if (tid < 64) {
            int i = tid;
            float f = fw[o];
            const float* cwp = cw + ((size_t)o * HH + i) * KW;
            float w0 = cwp[0], w1 = cwp[1], w2 = cwp[2], w3 = cwp[3], w4 = cwp[4];
            float* xp = Xpart + (size_t)o * 576 + i;
            xp[0]       = f * (w0 + w1 + w2 + w3 + w4);   // v=0 (G)
            xp[64]      = f * (w1 + w2 + w3 + w4);        // v=1 (H_0)
            xp[128]     = f * (w2 + w3 + w4);
            xp[192]     = f * (w3 + w4);
            xp[256]     = f * w4;
            xp[320]     = f * w0;
            xp[384]     = f * (w0 + w1);
            xp[448]     = f * (w0 + w1 + w2);
            xp[512]     = f * (w0 + w1 + w2 + w3);        // v=8 (H_7)
        }
        return;
    }
    // ---- bw2 block: bw2[i] = sum_h b1[h] * W2[h,i] ----
    {
        __shared__ float W2s[64 * 65];   // padded: bank-conflict-free column dots
        __shared__ float b1s[64];
        for (int idx = tid; idx < 64 * 64; idx += 256)
            W2s[(idx >> 6) * 65 + (idx & 63)] = W2[idx];
        if (tid < 64) b1s[tid] = b1[tid];
        __syncthreads();
        if (tid < 64) {
            float s = 0.f;
            #pragma unroll 8
            for (int h = 0; h < 64; ++h) s += b1s[h] * W2s[h * 65 + tid];
            bw2[tid] = s;
        }
    }
}

// kC: blocks 0..511 stream A for partial d (+ per-chunk c sums);
//     blocks 512..520: per-v adjoint tail (X reduce, P, M, alpha/beta/gamma).
// grid 521, block 256
__global__ __launch_bounds__(256) void kC(const float4* __restrict__ A4,
                                          const float* __restrict__ part1f,
                                          float4* __restrict__ partD,
                                          float* __restrict__ sCpart,
                                          const float* __restrict__ Xpart,
                                          const float* __restrict__ bw2,
                                          const float* __restrict__ W1,
                                          const float* __restrict__ W2,
                                          const float* __restrict__ b2,
                                          const float* __restrict__ cb,
                                          const float* __restrict__ fw,
                                          const float* __restrict__ fb,
                                          float* __restrict__ Mout,
                                          float* __restrict__ AB,
                                          float* __restrict__ G9) {
    int tid = threadIdx.x;
    if (blockIdx.x < 512) {
        int bx = blockIdx.x & 15, by = blockIdx.x >> 4;
        int tx = tid & 63, ty = tid >> 6;
        __shared__ float cs[CHUNK];
        __shared__ float4 redd[4][64];
        int m0 = by * CHUNK;
        if (tid < CHUNK) {
            float s = 0.f;
            #pragma unroll 8
            for (int y = 0; y < RC; ++y) s += part1f[(size_t)y * NN + m0 + tid];
            cs[tid] = s;
        }
        __syncthreads();
        if (bx == 0 && tid < 64) {
            float t = cs[tid] + cs[tid + 64];
            for (int off = 32; off > 0; off >>= 1) t += __shfl_down(t, off);
            if (tid == 0) sCpart[by] = t;
        }
        int c4 = bx * 64 + tx;
        const float4* Ap = A4 + (size_t)(m0 + ty * 32) * COL4 + c4;
        float4 acc = {0.f, 0.f, 0.f, 0.f};
        #pragma unroll 8
        for (int j = 0; j < 32; ++j) f4fma(acc, cs[ty * 32 + j], Ap[(size_t)j * COL4]);
        redd[ty][tx] = acc;
        __syncthreads();
        if (ty == 0) {
            float4 t = redd[0][tx];
            f4add(t, redd[1][tx]);
            f4add(t, redd[2][tx]);
            f4add(t, redd[3][tx]);
            partD[(size_t)by * COL4 + c4] = t;
        }
        return;
    }
    // ---- adjoint tail, one block per v ----
    int v = blockIdx.x - 512;
    __shared__ float W2s[64 * 65];    // 16.6 KB, padded
    __shared__ float W1s[40 * 65];    // 10.4 KB, padded
    __shared__ float Xs[64];
    __shared__ float Ps[64];
    __shared__ float bw2s[64];
    __shared__ float b2s[64];
    __shared__ float fcb_s;
    for (int idx = tid; idx < 64 * 64; idx += 256)
        W2s[(idx >> 6) * 65 + (idx & 63)] = W2[idx];
    for (int idx = tid; idx < 40 * 64; idx += 256)
        W1s[(idx >> 6) * 65 + (idx & 63)] = W1[idx];
    if (tid < 64) { bw2s[tid] = bw2[tid]; b2s[tid] = b2[tid]; }
    if (tid == 0) fcb_s = 0.f;
    __syncthreads();
    // X[v][i] = sign * sum_o Xpart[o][v][i] / LL
    if (tid < 64) {
        float s = 0.f;
        #pragma unroll 8
        for (int o = 0; o < 64; ++o) s += Xpart[(size_t)o * 576 + v * 64 + tid];
        Xs[tid] = (v == 0 ? 1.f : -1.f) * s / (float)LL;
    }
    __syncthreads();
    // P[h] = sum_i X[i] * W2[h,i]
    if (tid < 64) {
        float s = 0.f;
        #pragma unroll 8
        for (int i = 0; i < 64; ++i) s += Xs[i] * W2s[tid * 65 + i];
        Ps[tid] = s;
    }
    __syncthreads();
    // M[v][f] = sum_h P[h] * W1[f,h]  |  AB[v] = X·bw2  |  fcb (v==0)
    if (tid < F_IN) {
        float s = 0.f;
        #pragma unroll 8
        for (int h = 0; h < 64; ++h) s += Ps[h] * W1s[tid * 65 + h];
        Mout[v * F_IN + tid] = s;
    }
    if (tid >= 64 && tid < 128) {
        int i = tid - 64;
        float a = Xs[i] * bw2s[i];
        for (int off = 32; off > 0; off >>= 1) a += __shfl_down(a, off);
        if (i == 0) AB[v] = a;
    }
    if (v == 0 && tid >= 128 && tid < 192) {
        int o = tid - 128;
        float t = fw[o] * cb[o];
        for (int off = 32; off > 0; off >>= 1) t += __shfl_down(t, off);
        if (o == 0) fcb_s = t;
    }
    __syncthreads();
    // G9[v] = sum_i X[i]*(v==0 ? N*b2[i] : b2[i])  (+ fcb + fb for v==0)
    if (tid < 64) {
        float g = Xs[tid] * (v == 0 ? (float)NN * b2s[tid] : b2s[tid]);
        for (int off = 32; off > 0; off >>= 1) g += __shfl_down(g, off);
        if (tid == 0) G9[v] = g + (v == 0 ? fcb_s + fb[0] : 0.f);
    }
}

// x-contraction with on-the-fly partial reduction + dot with M.
// grid (BB, PC), block 256
__global__ __launch_bounds__(256) void kE(const float* __restrict__ x,
                                          const float* __restrict__ partDf,
                                          const float* __restrict__ partEf,
                                          const float* __restrict__ M,
                                          float* __restrict__ spart) {
    __shared__ float xs[PCH * F_IN];   // 40 KB
    __shared__ float wls[9][PCH];      // 9 KB
    __shared__ float Ms[9 * F_IN];
    __shared__ float red[256];
    int b = blockIdx.x, pc = blockIdx.y;
    int tid = threadIdx.x;
    int p0 = pc * PCH;
    const float4* xsrc4 = (const float4*)(x + ((size_t)b * NN + p0) * F_IN);
    float4* xs4 = (float4*)xs;
    #pragma unroll 4
    for (int idx = tid; idx < PCH * F_IN / 4; idx += 256) xs4[idx] = xsrc4[idx];
    for (int idx = tid; idx < 9 * PCH4; idx += 256) {
        int v = idx / PCH4, j4 = idx % PCH4;
        float4 s = {0.f, 0.f, 0.f, 0.f};
        if (v == 0) {
            #pragma unroll 8
            for (int y = 0; y < RC; ++y)
                f4add(s, ((const float4*)partDf)[(size_t)y * COL4 + pc * PCH4 + j4]);
        } else {
            #pragma unroll 8
            for (int y = 0; y < RC; ++y)
                f4add(s, ((const float4*)partEf)[((size_t)y * 8 + (v - 1)) * COL4 + pc * PCH4 + j4]);
        }
        ((float4*)&wls[v][0])[j4] = s;
    }
    for (int idx = tid; idx < 9 * F_IN; idx += 256) Ms[idx] = M[idx];
    __syncthreads();
    float part = 0.f;
    for (int o = tid; o < 9 * F_IN; o += 256) {
        int v = o / F_IN, f = o % F_IN;
        float s = 0.f;
        for (int j = 0; j < PCH; ++j) s += wls[v][j] * xs[j * F_IN + f];
        part += Ms[o] * s;
    }
    red[tid] = part;
    __syncthreads();
    for (int off = 128; off > 0; off >>= 1) {
        if (tid < off) red[tid] += red[tid + off];
        __syncthreads();
    }
    if (tid == 0) spart[(size_t)b * PC + pc] = red[0];
}

// kF: c0 = sum_v G9[v] + alpha*sC + sum_s beta_s*r_s ; out[b] = c0 + sum_pc spart.
// grid 1, block 128
__global__ void kF(const float* __restrict__ spart, const float* __restrict__ rpart,
                   const float* __restrict__ sCpart, const float* __restrict__ AB,
                   const float* __restrict__ G9, float* __restrict__ out) {
    int tid = threadIdx.x;
    __shared__ float red[128];
    __shared__ float c0s;
    float val = AB[1 + (tid >> 4)] * rpart[tid];    // beta_s * rpart[s][g]
    if (tid < 32) val += AB[0] * sCpart[tid];       // alpha * sC partials
    if (tid < 9)  val += G9[tid];                   // gamma pieces
    red[tid] = val;
    __syncthreads();
    for (int off = 64; off > 0; off >>= 1) {
        if (tid < off) red[tid] += red[tid + off];
        __syncthreads();
    }
    if (tid == 0) c0s = red[0];
    __syncthreads();
    float s = spart[tid];                            // b=tid>>4, i=tid&15
    for (int off = 8; off > 0; off >>= 1) s += __shfl_down(s, off, 16);
    if ((tid & 15) == 0) out[tid >> 4] = c0s + s;
}

extern "C" void kernel_launch(void* const* d_in, const int* in_sizes, int n_in,
                              void* d_out, int out_size, void* d_ws, size_t ws_size,
                              hipStream_t stream) {
    const float* x  = (const float*)d_in[0];
    const float* A  = (const float*)d_in[1];
    const float* W1 = (const float*)d_in[2];
    const float* b1 = (const float*)d_in[3];
    const float* W2 = (const float*)d_in[4];
    const float* b2 = (const float*)d_in[5];
    const float* cw = (const float*)d_in[6];
    const float* cb = (const float*)d_in[7];
    const float* fw = (const float*)d_in[8];
    const float* fb = (const float*)d_in[9];
    float* out = (float*)d_out;
    float* ws = (float*)d_ws;

    float* part1 = ws + OFF_P1;
    float* partE = ws + OFF_PE;
    float* partD = ws + OFF_PD;
    float* Xpart = ws + OFF_XP;
    float* bw2   = ws + OFF_BW;
    float* Mmat  = ws + OFF_M;
    float* AB    = ws + OFF_AB;
    float* G9    = ws + OFF_G9;
    float* rpart = ws + OFF_RP;
    float* sCpart= ws + OFF_SC;
    float* spart = ws + OFF_SP;

    const float4* A4 = (const float4*)A;

    kA<<<dim3(577), dim3(64, 4), 0, stream>>>(A4, A, (float4*)part1, (float4*)partE, rpart,
                                              b1, W2, cw, fw, Xpart, bw2);
    kC<<<dim3(521), 256, 0, stream>>>(A4, part1, (float4*)partD, sCpart,
                                      Xpart, bw2, W1, W2, b2, cb, fw, fb, Mmat, AB, G9);
    kE<<<dim3(BB, PC), 256, 0, stream>>>(x, partD, partE, Mmat, spart);
    kF<<<dim3(1), 128, 0, stream>>>(spart, rpart, sCpart, AB, G9, out);
}